// Round 4
// baseline (353.971 us; speedup 1.0000x reference)
//
#include <hip/hip_runtime.h>
#include <stdint.h>

#define BATCH_N   131072
#define HID       256
#define SPIKE_DIM 128
#define COORD_DIM 64
#define IN_DIM    192
#define STEPS     25
#define TILE      64
#define SUBT      4          // tiles per block (pipelined)
#define BLOCK     512

typedef float f4  __attribute__((ext_vector_type(4)));
typedef short bf8 __attribute__((ext_vector_type(8)));
typedef unsigned short us4 __attribute__((ext_vector_type(4)));

// ws layout:
//   W0b  [256][192] bf16   at byte 0        (49152 ushorts = 96 KB)
//   W1T  [256][256] fp32   at float 24576   (65536 floats)
//   WoT  [256][64]  fp32   at float 90112   (16384 floats)
//   scalars           at float 106496: [0]=max(b1,0), [1]=max(W1+,0)
#define W1T_OFF  24576
#define WOT_OFF  90112
#define SCAL_OFF 106496

static __device__ __forceinline__ unsigned short f2bf(float f) {
  union { float f; unsigned u; } v; v.f = f;
  unsigned r = v.u + 0x7FFF + ((v.u >> 16) & 1);   // RNE
  return (unsigned short)(r >> 16);
}

__global__ __launch_bounds__(256)
void prep_kernel(const float* __restrict__ W0,
                 const float* __restrict__ W1,
                 const float* __restrict__ Wout,
                 const float* __restrict__ b1,
                 float* __restrict__ ws) {
  // Screen scalars via parallel wave-reduce + atomicMax on float bits
  // (values are >=0 after the fmaxf(.,0) fold, so uint order == float
  // order). ws[SCAL_OFF..+1] is zeroed by hipMemsetAsync before launch;
  // atomicMax then yields the exact max (R1 lesson: never one serial
  // reduction block; R3 lesson: keep prep off the critical path).
  const int t = threadIdx.x, b = blockIdx.x;
  if (b == 512) {
    unsigned u = __float_as_uint(fmaxf(b1[t], 0.f));
    #pragma unroll
    for (int o = 1; o < 64; o <<= 1) {
      unsigned v = __shfl_xor(u, o);
      u = v > u ? v : u;
    }
    if ((t & 63) == 0) atomicMax((unsigned*)(ws + SCAL_OFF), u);
    return;
  }
  int idx = b * 256 + t;
  if (idx < HID*IN_DIM) {               // W0b elementwise (row-major, k-contig)
    ((unsigned short*)ws)[idx] = f2bf(W0[idx]);
  }
  int i1 = idx - HID*IN_DIM;            // W1T[j][i] = W1[i][j]
  if (i1 >= 0 && i1 < HID*HID) {
    int j = i1 >> 8, i = i1 & 255;
    ws[W1T_OFF + i1] = W1[i*HID + j];
  }
  int i2 = idx - (HID*IN_DIM + HID*HID);// WoT[k][c] = Wout[128+c][k]
  if (i2 >= 0 && i2 < HID*COORD_DIM) {
    int k = i2 >> 6, c = i2 & 63;
    ws[WOT_OFF + i2] = Wout[(SPIKE_DIM + c)*HID + k];
  }
  if (b < 64) {                         // W1 max: 64 blocks cover 16384 f4
    f4 v = ((const f4*)W1)[idx];
    float m = fmaxf(fmaxf(v.x, v.y), fmaxf(v.z, v.w));
    m = fmaxf(m, 0.f);
    unsigned u = __float_as_uint(m);
    #pragma unroll
    for (int o = 1; o < 64; o <<= 1) {
      unsigned w = __shfl_xor(u, o);
      u = w > u ? w : u;
    }
    if ((t & 63) == 0) atomicMax((unsigned*)(ws + SCAL_OFF + 1), u);
  }
}

// ---- staging macros: issue-early (loads->regs), write-late (convert->LDS)
#define STAGE_LOAD(e0n)                                              \
  {                                                                  \
    const f4* sp4 = (const f4*)(spk + (size_t)(e0n) * SPIKE_DIM);    \
    const f4* cr4 = (const f4*)(crd + (size_t)(e0n) * COORD_DIM);    \
    r0 = __builtin_nontemporal_load(&sp4[tid]);                      \
    r1 = __builtin_nontemporal_load(&sp4[tid + 512]);                \
    r2 = __builtin_nontemporal_load(&sp4[tid + 1024]);               \
    r3 = __builtin_nontemporal_load(&sp4[tid + 1536]);               \
    r4 = __builtin_nontemporal_load(&cr4[tid]);                      \
    r5 = __builtin_nontemporal_load(&cr4[tid + 512]);                \
  }

#define CV(h, r) { h.x = f2bf(r.x); h.y = f2bf(r.y); h.z = f2bf(r.z); h.w = f2bf(r.w); }

#define STAGE_WRITE(dst)                                             \
  {                                                                  \
    const int es = tid >> 5, js = (tid & 31) * 4;                    \
    const int ec = tid >> 4, jc = SPIKE_DIM + (tid & 15) * 4;        \
    us4 h;                                                           \
    CV(h, r0) *(us4*)&(dst)[(es     )*200 + js] = h;                 \
    CV(h, r1) *(us4*)&(dst)[(es + 16)*200 + js] = h;                 \
    CV(h, r2) *(us4*)&(dst)[(es + 32)*200 + js] = h;                 \
    CV(h, r3) *(us4*)&(dst)[(es + 48)*200 + js] = h;                 \
    CV(h, r4) *(us4*)&(dst)[(ec     )*200 + jc] = h;                 \
    CV(h, r5) *(us4*)&(dst)[(ec + 32)*200 + jc] = h;                 \
  }

__global__ __launch_bounds__(BLOCK, 4)
void snn_kernel(const float* __restrict__ spk,
                const float* __restrict__ crd,
                const float* __restrict__ W0,
                const float* __restrict__ b0,
                const float* __restrict__ b1,
                const float* __restrict__ bout,
                const float* __restrict__ ws,
                float* __restrict__ out) {
  // R4: pipelined block over SUBT=4 tiles of 64 elements.
  //   * B fragments (12/wave) + biases + screen scalars loaded ONCE/block,
  //     amortized over 4 tiles (R3 paid them per tile, 2048x).
  //   * xb double-buffered: tile t+1's HBM loads issued before tile t's
  //     MFMA (T14 issue-early/write-late) -> ~900cy load latency hidden.
  //   * m-loop split in halves: acc 16 regs not 32; peak VGPR ~112 < 128
  //     so 2 blocks/CU co-schedule.
  __shared__ unsigned short sbuf[2*TILE*200]; // 51.2 KB, two x-tile buffers
  __shared__ unsigned cnt2[2*32];             // per-buffer packed counts

  const int tid  = threadIdx.x;
  const int lane = tid & 63;
  const int wv   = tid >> 6;            // wave 0..7
  const int quad = lane >> 4;
  const int l15  = lane & 15;
  const int i4   = lane * 4;
  const int tile0 = blockIdx.x * SUBT;

  if (tid < 64) cnt2[tid] = 0;

  f4 r0, r1, r2, r3, r4, r5;
  STAGE_LOAD(tile0 * TILE)              // tile 0 loads in flight...

  // ...overlapped with per-block constants:
  const unsigned short* W0b = (const unsigned short*)ws;  // [256][192]
  float b0n[2];
  b0n[0] = b0[wv*32 + l15];
  b0n[1] = b0[wv*32 + 16 + l15];
  bf8 bfr[2][6];                        // 12 KB of W0b rows, reg-resident
  #pragma unroll
  for (int n = 0; n < 2; ++n)
    #pragma unroll
    for (int kc = 0; kc < 6; ++kc)
      bfr[n][kc] = *(const bf8*)&W0b[(size_t)(wv*32 + n*16 + l15)*IN_DIM
                                     + kc*32 + quad*8];
  const float b1mx = ws[SCAL_OFF];
  const float w1pm = ws[SCAL_OFF + 1];
  const float bc = bout[SPIKE_DIM + lane];
  const int eb = wv * 8;

  STAGE_WRITE(sbuf)                     // prologue: publish tile 0
  __syncthreads();

  for (int s = 0; s < SUBT; ++s) {
    unsigned short* bufc = &sbuf[(s & 1) * TILE*200];
    unsigned short* bufn = &sbuf[((s + 1) & 1) * TILE*200];
    unsigned* cw = &cnt2[(s & 1) * 32];
    const int e0s = (tile0 + s) * TILE;
    const bool more = (s + 1 < SUBT);

    if (more) STAGE_LOAD((tile0 + s + 1) * TILE)   // issue-early

    // ---- MFMA (m split in halves: acc 16 regs) + spike-superset counts.
    // C/D layout: col(neuron)=l15, row(element)=m*16+quad*4+reg.
    // Rigor: exact-spiking neuron has exact c0 >= 0.96; bf16-input MFMA
    // error <= ~0.05 (f32 accumulate) -> acc+b0 >= 0.90 counts it.
    #pragma unroll
    for (int mh = 0; mh < 2; ++mh) {
      f4 acc[2][2];
      #pragma unroll
      for (int m = 0; m < 2; ++m)
        #pragma unroll
        for (int n = 0; n < 2; ++n)
          { acc[m][n].x = acc[m][n].y = acc[m][n].z = acc[m][n].w = 0.f; }
      #pragma unroll
      for (int kc = 0; kc < 6; ++kc) {
        #pragma unroll
        for (int m = 0; m < 2; ++m) {
          bf8 a = *(const bf8*)&bufc[((mh*2 + m)*16 + l15)*200 + kc*32 + quad*8];
          acc[m][0] = __builtin_amdgcn_mfma_f32_16x16x32_bf16(a, bfr[0][kc], acc[m][0], 0, 0, 0);
          acc[m][1] = __builtin_amdgcn_mfma_f32_16x16x32_bf16(a, bfr[1][kc], acc[m][1], 0, 0, 0);
        }
      }
      #pragma unroll
      for (int m = 0; m < 2; ++m) {
        unsigned lo = 0, hi = 0;
        #pragma unroll
        for (int n = 0; n < 2; ++n) {
          lo += (acc[m][n].x + b0n[n] >= 0.90f) ? 1u       : 0u;
          lo += (acc[m][n].y + b0n[n] >= 0.90f) ? (1u<<16) : 0u;
          hi += (acc[m][n].z + b0n[n] >= 0.90f) ? 1u       : 0u;
          hi += (acc[m][n].w + b0n[n] >= 0.90f) ? (1u<<16) : 0u;
        }
        lo += __shfl_xor(lo, 1, 16); hi += __shfl_xor(hi, 1, 16);
        lo += __shfl_xor(lo, 2, 16); hi += __shfl_xor(hi, 2, 16);
        lo += __shfl_xor(lo, 4, 16); hi += __shfl_xor(hi, 4, 16);
        lo += __shfl_xor(lo, 8, 16); hi += __shfl_xor(hi, 8, 16);
        if (l15 == 0) {
          atomicAdd(&cw[((mh*2 + m)*4 + quad)*2 + 0], lo);
          atomicAdd(&cw[((mh*2 + m)*4 + quad)*2 + 1], hi);
        }
      }
    }
    __syncthreads();                    // counts complete; bufn free to write

    // ---- screen (no loads) -> bulk stores; rare exact fallback ----
    // c1_i(t) <= max(b1,0) + nspk * max(W1+,0) < 0.97 => s1 == 0 =>
    // outputs (0, b_out) EXACT. Garbage scalars fail closed (exact path).
    unsigned fastm = 0;
    #pragma unroll
    for (int ee = 0; ee < 8; ++ee) {
      const int el = eb + ee;
      unsigned w = cw[(el >> 2)*2 + ((el >> 1) & 1)];
      unsigned nspk = (w >> ((el & 1)*16)) & 0xFFFFu;
      if (b1mx + w1pm * (float)nspk < 0.97f) fastm |= (1u << ee);
    }
    if (lane < 4) cw[wv*4 + lane] = 0;  // own disjoint slice; reuse at s+2

    #pragma unroll
    for (int ee = 0; ee < 8; ++ee) {
      if (fastm & (1u << ee)) {
        const int e = e0s + eb + ee;
        f4 z; z.x = z.y = z.z = z.w = 0.f;
        __builtin_nontemporal_store(z, (f4*)&out[(size_t)e*HID + i4]);
        __builtin_nontemporal_store(bc,
            &out[(size_t)BATCH_N*HID + (size_t)e*COORD_DIM + lane]);
      }
    }

    // rare (~P 3e-5/element): verbatim exact path
    if (__builtin_expect(fastm != 0xFFu, 0)) {
      const float* W1T = ws + W1T_OFF;
      const float* WoT = ws + WOT_OFF;
      f4 b0v = *(const f4*)&b0[i4];
      f4 b1v = *(const f4*)&b1[i4];
      for (int ee = 0; ee < 8; ++ee) {
        if (fastm & (1u << ee)) continue;
        const int e = e0s + eb + ee;

        // ---- exact c0 recompute from global x, W0 (serial FMA, j ascending)
        float cx = 0.f, cy = 0.f, cz = 0.f, cw_ = 0.f;
        const float* q0 = W0 + (size_t)(i4+0)*IN_DIM;
        const float* q1 = W0 + (size_t)(i4+1)*IN_DIM;
        const float* q2 = W0 + (size_t)(i4+2)*IN_DIM;
        const float* q3 = W0 + (size_t)(i4+3)*IN_DIM;
        const float* xs_ = spk + (size_t)e*SPIKE_DIM;
        const float* xc_ = crd + (size_t)e*COORD_DIM;
        for (int j = 0; j < SPIKE_DIM; ++j) {
          float xj = xs_[j];
          cx = fmaf(xj, q0[j], cx); cy = fmaf(xj, q1[j], cy);
          cz = fmaf(xj, q2[j], cz); cw_ = fmaf(xj, q3[j], cw_);
        }
        for (int j = 0; j < COORD_DIM; ++j) {
          float xj = xc_[j];
          cx = fmaf(xj, q0[SPIKE_DIM+j], cx); cy = fmaf(xj, q1[SPIKE_DIM+j], cy);
          cz = fmaf(xj, q2[SPIKE_DIM+j], cz); cw_ = fmaf(xj, q3[SPIKE_DIM+j], cw_);
        }
        const float c0x = cx + b0v.x, c0y = cy + b0v.y;
        const float c0z = cz + b0v.z, c0w = cw_ + b0v.w;

        // ---- honest 25-step simulation (exact)
        float v0x=0.f, v0y=0.f, v0z=0.f, v0w=0.f;
        float v1x=0.f, v1y=0.f, v1z=0.f, v1w=0.f;
        float s1x=0.f, s1y=0.f, s1z=0.f, s1w=0.f;
        unsigned long long mm;

        for (int t = 0; t < STEPS; ++t) {
          bool sp;
          unsigned long long m0, m1, m2, m3;
          v0x = __fmul_rn(0.7f, v0x) + __fmul_rn(0.3f, c0x);
          sp = (v0x >= 1.0f); m0 = __ballot(sp); if (sp) v0x = 0.f;
          v0y = __fmul_rn(0.7f, v0y) + __fmul_rn(0.3f, c0y);
          sp = (v0y >= 1.0f); m1 = __ballot(sp); if (sp) v0y = 0.f;
          v0z = __fmul_rn(0.7f, v0z) + __fmul_rn(0.3f, c0z);
          sp = (v0z >= 1.0f); m2 = __ballot(sp); if (sp) v0z = 0.f;
          v0w = __fmul_rn(0.7f, v0w) + __fmul_rn(0.3f, c0w);
          sp = (v0w >= 1.0f); m3 = __ballot(sp); if (sp) v0w = 0.f;

          float c1x = b1v.x, c1y = b1v.y, c1z = b1v.z, c1w = b1v.w;
          f4 wcur; wcur.x = wcur.y = wcur.z = wcur.w = 0.f;
          int have = 0;
          #define PROCQ(MASK, Q)                                                  \
            mm = (MASK);                                                          \
            while (mm) {                                                          \
              int l = __builtin_ctzll(mm); mm &= mm - 1;                          \
              f4 wn = *(const f4*)&W1T[(l*4 + (Q))*HID + i4];                     \
              if (have) { c1x += wcur.x; c1y += wcur.y; c1z += wcur.z; c1w += wcur.w; } \
              wcur = wn; have = 1;                                                \
            }
          PROCQ(m0, 0)
          PROCQ(m1, 1)
          PROCQ(m2, 2)
          PROCQ(m3, 3)
          #undef PROCQ
          if (have) { c1x += wcur.x; c1y += wcur.y; c1z += wcur.z; c1w += wcur.w; }

          v1x = __fmul_rn(0.7f, v1x) + __fmul_rn(0.3f, c1x);
          sp = (v1x >= 1.0f); s1x = sp ? 1.f : 0.f; if (sp) v1x = 0.f;
          v1y = __fmul_rn(0.7f, v1y) + __fmul_rn(0.3f, c1y);
          sp = (v1y >= 1.0f); s1y = sp ? 1.f : 0.f; if (sp) v1y = 0.f;
          v1z = __fmul_rn(0.7f, v1z) + __fmul_rn(0.3f, c1z);
          sp = (v1z >= 1.0f); s1z = sp ? 1.f : 0.f; if (sp) v1z = 0.f;
          v1w = __fmul_rn(0.7f, v1w) + __fmul_rn(0.3f, c1w);
          sp = (v1w >= 1.0f); s1w = sp ? 1.f : 0.f; if (sp) v1w = 0.f;
        }

        f4 res; res.x = s1x; res.y = s1y; res.z = s1z; res.w = s1w;
        __builtin_nontemporal_store(res, (f4*)&out[(size_t)e*HID + i4]);

        unsigned long long f0 = __ballot(s1x > 0.5f);
        unsigned long long f1 = __ballot(s1y > 0.5f);
        unsigned long long f2 = __ballot(s1z > 0.5f);
        unsigned long long f3 = __ballot(s1w > 0.5f);
        float cacc = bc;
        #define CPROCQ(MASK, Q)                                 \
          mm = (MASK);                                          \
          while (mm) {                                          \
            int l = __builtin_ctzll(mm); mm &= mm - 1;          \
            cacc += WoT[(l*4 + (Q))*COORD_DIM + lane];          \
          }
        CPROCQ(f0, 0)
        CPROCQ(f1, 1)
        CPROCQ(f2, 2)
        CPROCQ(f3, 3)
        #undef CPROCQ
        __builtin_nontemporal_store(cacc,
            &out[(size_t)BATCH_N*HID + (size_t)e*COORD_DIM + lane]);
      }
    }

    if (more) {
      STAGE_WRITE(bufn)                 // write-late: after vmcnt on r0..r5
      __syncthreads();                  // publish tile s+1
    }
  }
}

extern "C" void kernel_launch(void* const* d_in, const int* in_sizes, int n_in,
                              void* d_out, int out_size, void* d_ws, size_t ws_size,
                              hipStream_t stream) {
  (void)in_sizes; (void)n_in; (void)out_size; (void)ws_size;
  const float* spk = (const float*)d_in[0];
  const float* crd = (const float*)d_in[1];
  const float* W0  = (const float*)d_in[2];
  const float* b0  = (const float*)d_in[3];
  const float* W1  = (const float*)d_in[4];
  const float* b1  = (const float*)d_in[5];
  const float* Wo  = (const float*)d_in[6];
  const float* bo  = (const float*)d_in[7];
  float* ws  = (float*)d_ws;
  float* out = (float*)d_out;

  hipMemsetAsync(ws + SCAL_OFF, 0, 8, stream);   // seed for atomicMax
  hipLaunchKernelGGL(prep_kernel, dim3(513), dim3(256), 0, stream, W0, W1, Wo, b1, ws);
  hipLaunchKernelGGL(snn_kernel, dim3(BATCH_N/(TILE*SUBT)), dim3(BLOCK), 0, stream,
                     spk, crd, W0, b0, b1, bo, ws, out);
}